// Round 3
// baseline (259.186 us; speedup 1.0000x reference)
//
#include <hip/hip_runtime.h>
#include <cstdint>
#include <math.h>

// ---------------------------------------------------------------------------
// CausalSelfAttention (B=4, T=2048, D=1024, H=16, Dh=64), fp32 in/out,
// bf16 MFMA compute internally.
// Pipeline: fused cast -> fused QKV GEMM (256x256 tile, BK=64, 8-phase
//           fine-interleaved schedule, counted vmcnt, XOR-swizzled LDS,
//           V transposed in epilogue, 384 blocks) -> flash attention
//           (unchanged) -> output projection (same template, BN=128,
//           256 blocks = 1 exact CU round, fp32 out).
// Round-3 delta vs round-2 (which died without a verdict): all barriers are
// __builtin_amdgcn_s_barrier() (convergent, compiler-known) instead of raw
// asm, and every inline-asm s_waitcnt is followed by sched_barrier(0).
// ---------------------------------------------------------------------------

typedef unsigned short u16;
typedef __bf16 bf16x8 __attribute__((ext_vector_type(8)));
typedef __bf16 bf16x4 __attribute__((ext_vector_type(4)));
typedef float f32x4 __attribute__((ext_vector_type(4)));

__device__ __forceinline__ u16 f32_bf16(float f) {  // round-nearest-even
  union { float f; uint32_t u; } c; c.f = f;
  uint32_t u = c.u;
  return (u16)((u + 0x7FFFu + ((u >> 16) & 1u)) >> 16);
}

__device__ __forceinline__ f32x4 mfma16(bf16x8 a, bf16x8 b, f32x4 c) {
  return __builtin_amdgcn_mfma_f32_16x16x32_bf16(a, b, c, 0, 0, 0);
}

// async global->LDS, 16B/lane. LDS dest must be wave-uniform base + lane*16.
__device__ __forceinline__ void gload_lds16(const u16* g, u16* l) {
  __builtin_amdgcn_global_load_lds(
      (const __attribute__((address_space(1))) void*)g,
      (__attribute__((address_space(3))) void*)l, 16, 0, 0);
}

__device__ __forceinline__ void wait_lgkm0() {
  asm volatile("s_waitcnt lgkmcnt(0)" ::: "memory");
  __builtin_amdgcn_sched_barrier(0);
}
template <int N>
__device__ __forceinline__ void wait_vm() {
  if (N == 6)      asm volatile("s_waitcnt vmcnt(6)" ::: "memory");
  else if (N == 4) asm volatile("s_waitcnt vmcnt(4)" ::: "memory");
  else if (N == 2) asm volatile("s_waitcnt vmcnt(2)" ::: "memory");
  else if (N == 0) asm volatile("s_waitcnt vmcnt(0)" ::: "memory");
  __builtin_amdgcn_sched_barrier(0);
}

// barrier that does NOT drain the newest 2 vm loads (attn t+2 prefetch)
__device__ __forceinline__ void barrier_vm2() {
  asm volatile("s_waitcnt vmcnt(2)" ::: "memory");
  __builtin_amdgcn_sched_barrier(0);
  __builtin_amdgcn_s_barrier();
}

// ---------------------------------------------------------------------------
// fused cast fp32->bf16 of x + 4 weights into contiguous ws region
// ---------------------------------------------------------------------------
__global__ __launch_bounds__(256) void cvt_all_kernel(
    const float* __restrict__ x,
    const float* __restrict__ wq, const float* __restrict__ wk,
    const float* __restrict__ wv, const float* __restrict__ wo,
    u16* __restrict__ dst, int n_x, int n_w) {
  int i = blockIdx.x * 256 + threadIdx.x;
  const float* src;
  int off;
  if (i < n_x) { src = x; off = i; }
  else {
    int j = i - n_x;
    int w = j / n_w;  off = j - w * n_w;
    src = (w == 0) ? wq : (w == 1) ? wk : (w == 2) ? wv : wo;
  }
  float4 f = ((const float4*)src)[off];
  ushort4 o;
  o.x = f32_bf16(f.x); o.y = f32_bf16(f.y);
  o.z = f32_bf16(f.z); o.w = f32_bf16(f.w);
  ((ushort4*)dst)[i] = o;
}

// ---------------------------------------------------------------------------
// 8-phase GEMM: C[m,n] = scale * sum_k A[m,k]*B[n,k] (both K-contiguous).
// BM=256, BN=NS*64 (NS=4: 256, NS=2: 128), BK=64, 512 threads = 8 waves
// (2M x 4N), per-wave 128 x NS*16 output. LDS double-buffered:
// As[2][256*64] (64 KB) + Bs[2][BN*64] (64/32 KB).
//
// Per K-tile: 4 phases, phase p=(mh,nh)=(p>>1,p&1) computes quadrant
// acc[mh*4..+4][nh*NB..+NB] over K=64 (16 MFMA at NS=4, 8 at NS=2):
//   [issue ds_reads for this quadrant | issue 2 staging gload_lds]
//   s_barrier ; s_waitcnt lgkmcnt(0)
//   setprio(1) ; MFMA cluster ; setprio(0) ; s_barrier
// Fragment reuse: af (8 reads) issued at nh=0, reused at nh=1; bf pairs
// (2*NB reads) issued at mh=0, reused at mh=1.  ds_read and MFMA overlap
// across waves via the per-phase stagger (the round-1 coarse schedule
// serialized 640cy LDS vs 1030cy MFMA per tile -> MfmaUtil 30%).
//
// Staging (counted vmcnt, never 0 in main loop): tile t's phases stage
//   ph0/ph1: A(t+1) into the OTHER buffer (prev contents consumed in t-1)
//   ph2/ph3: B(t+2) into the CURRENT buffer's B (B(t) consumed end-ph1;
//            all waves' reads complete before any ph2 stage issues)
// End of tile: vmcnt(NS) after ph3's MFMA (leaves B(t+2) in flight),
// guaranteeing tile t+1 fully landed before its ph0 ds_reads.
// Tail: t=14 stages A(15) only + vmcnt(0); t=15 no stage, no wait.
//
// LDS swizzle (verified round 1, 0 bank conflicts): LDS[row][c] =
// G[row][c ^ (row&7)] via pre-swizzled global source; reads use
// chunk = (quad^(l15&3)) + kof-bit so content collapses to canonical
// A[row][quad*8 + kh*32].
// ---------------------------------------------------------------------------
template <int NS, bool SA, bool SB, int ENDW>  // ENDW: 4/2 counted, 0, -1 none
__device__ __forceinline__ void kiter8p(
    f32x4 (&acc)[8][NS],
    const u16* __restrict__ aCur, const u16* __restrict__ bCur,
    u16* aNxt, u16* bCurW, const u16* gaN, const u16* gbN2, int tid,
    int aoff0, int aoff1, int boff0, int boff1) {
  constexpr int NB = NS / 2;
  bf16x8 af[4][2], bfA[NB][2], bfB[NB][2];

  // ---- phase 0: (mh=0, nh=0) ----
#pragma unroll
  for (int m = 0; m < 4; ++m) {
    af[m][0] = *(const bf16x8*)(aCur + aoff0 + m * 1024);
    af[m][1] = *(const bf16x8*)(aCur + aoff1 + m * 1024);
  }
#pragma unroll
  for (int n = 0; n < NB; ++n) {
    bfA[n][0] = *(const bf16x8*)(bCur + boff0 + n * 1024);
    bfA[n][1] = *(const bf16x8*)(bCur + boff1 + n * 1024);
  }
  if (SA) {
    gload_lds16(gaN, aNxt + tid * 8);
    gload_lds16(gaN + 65536, aNxt + 4096 + tid * 8);
  }
  __builtin_amdgcn_s_barrier();
  wait_lgkm0();
  __builtin_amdgcn_s_setprio(1);
#pragma unroll
  for (int m = 0; m < 4; ++m)
#pragma unroll
    for (int n = 0; n < NB; ++n) {
      acc[m][n] = mfma16(af[m][0], bfA[n][0], acc[m][n]);
      acc[m][n] = mfma16(af[m][1], bfA[n][1], acc[m][n]);
    }
  __builtin_amdgcn_s_setprio(0);
  __builtin_amdgcn_s_barrier();

  // ---- phase 1: (mh=0, nh=1) ----
#pragma unroll
  for (int n = 0; n < NB; ++n) {
    bfB[n][0] = *(const bf16x8*)(bCur + boff0 + (NB + n) * 1024);
    bfB[n][1] = *(const bf16x8*)(bCur + boff1 + (NB + n) * 1024);
  }
  if (SA) {
    gload_lds16(gaN + 2 * 65536, aNxt + 2 * 4096 + tid * 8);
    gload_lds16(gaN + 3 * 65536, aNxt + 3 * 4096 + tid * 8);
  }
  __builtin_amdgcn_s_barrier();
  wait_lgkm0();
  __builtin_amdgcn_s_setprio(1);
#pragma unroll
  for (int m = 0; m < 4; ++m)
#pragma unroll
    for (int n = 0; n < NB; ++n) {
      acc[m][NB + n] = mfma16(af[m][0], bfB[n][0], acc[m][NB + n]);
      acc[m][NB + n] = mfma16(af[m][1], bfB[n][1], acc[m][NB + n]);
    }
  __builtin_amdgcn_s_setprio(0);
  __builtin_amdgcn_s_barrier();

  // ---- phase 2: (mh=1, nh=0) ----
#pragma unroll
  for (int m = 0; m < 4; ++m) {
    af[m][0] = *(const bf16x8*)(aCur + aoff0 + (4 + m) * 1024);
    af[m][1] = *(const bf16x8*)(aCur + aoff1 + (4 + m) * 1024);
  }
  if (SB) {
    gload_lds16(gbN2, bCurW + tid * 8);
    if (NS == 4) gload_lds16(gbN2 + 65536, bCurW + 4096 + tid * 8);
  }
  __builtin_amdgcn_s_barrier();
  wait_lgkm0();
  __builtin_amdgcn_s_setprio(1);
#pragma unroll
  for (int m = 0; m < 4; ++m)
#pragma unroll
    for (int n = 0; n < NB; ++n) {
      acc[4 + m][n] = mfma16(af[m][0], bfA[n][0], acc[4 + m][n]);
      acc[4 + m][n] = mfma16(af[m][1], bfA[n][1], acc[4 + m][n]);
    }
  __builtin_amdgcn_s_setprio(0);
  __builtin_amdgcn_s_barrier();

  // ---- phase 3: (mh=1, nh=1) ----
  if (SB) {
    if (NS == 4) {
      gload_lds16(gbN2 + 2 * 65536, bCurW + 2 * 4096 + tid * 8);
      gload_lds16(gbN2 + 3 * 65536, bCurW + 3 * 4096 + tid * 8);
    } else {
      gload_lds16(gbN2 + 65536, bCurW + 4096 + tid * 8);
    }
  }
  __builtin_amdgcn_s_barrier();
  __builtin_amdgcn_s_setprio(1);
#pragma unroll
  for (int m = 0; m < 4; ++m)
#pragma unroll
    for (int n = 0; n < NB; ++n) {
      acc[4 + m][NB + n] = mfma16(af[m][0], bfB[n][0], acc[4 + m][NB + n]);
      acc[4 + m][NB + n] = mfma16(af[m][1], bfB[n][1], acc[4 + m][NB + n]);
    }
  __builtin_amdgcn_s_setprio(0);
  if (ENDW == 4) wait_vm<4>();
  else if (ENDW == 2) wait_vm<2>();
  else if (ENDW == 0) wait_vm<0>();
  __builtin_amdgcn_s_barrier();
}

template <int MODE>  // 0 = QKV (NS=4, bf16 out, V transposed), 1 = proj (NS=2, fp32)
__global__ __launch_bounds__(512, 2) void gemm8p(
    const u16* __restrict__ A,
    const u16* __restrict__ B0, const u16* __restrict__ B1,
    const u16* __restrict__ B2,
    void* __restrict__ C0, void* __restrict__ C1, void* __restrict__ C2,
    float qscale) {
  constexpr int NS = (MODE == 0) ? 4 : 2;   // n-subtiles per wave
  constexpr int WN = NS * 16;               // per-wave N
  constexpr int K = 1024;
  __shared__ u16 As[2][16384];              // [dbuf][256 rows x 64 k]
  __shared__ u16 Bs[2][NS * 4096];          // [dbuf][BN rows x 64 k]

  // XCD-bijective decode: each XCD owns 4 row-strips, rt-minor order
  const int ord = blockIdx.x;
  const int xcd = ord & 7, g = ord >> 3;
  const int rt = xcd * 4 + (g & 3);
  const int ct = g >> 2;                    // MODE0: [0,12), MODE1: [0,8)
  const int z = (MODE == 0) ? (ct >> 2) : 0;
  const int colm = (MODE == 0) ? (ct & 3) * 256 : ct * 128;
  const int row0 = rt * 256;
  const u16* Bv = (z == 0) ? B0 : (z == 1) ? B1 : B2;

  const int tid = threadIdx.x;
  const int lane = tid & 63, wid = tid >> 6;
  const int quad = lane >> 4, l15 = lane & 15;
  const int wm = wid >> 2, wn = wid & 3;

  // staging: linear LDS dest, pre-swizzled global source
  const int srow = tid >> 3;
  const int selem = ((tid & 7) ^ (srow & 7)) * 8;
  const u16* ga = A + (size_t)(row0 + srow) * K + selem;
  const u16* gb = Bv + (size_t)(colm + srow) * K + selem;

  u16* pA0 = &As[0][0];
  u16* pA1 = &As[1][0];
  u16* pB0 = &Bs[0][0];
  u16* pB1 = &Bs[1][0];

  // swizzled fragment read offsets (elements)
  const int swz = 8 * (quad ^ (l15 & 3));
  const int kof = 32 * ((l15 >> 2) & 1);
  const int aoff0 = (wm * 128 + l15) * 64 + swz + kof;
  const int aoff1 = (wm * 128 + l15) * 64 + swz + (32 - kof);
  const int boff0 = (wn * WN + l15) * 64 + swz + kof;
  const int boff1 = (wn * WN + l15) * 64 + swz + (32 - kof);

  f32x4 acc[8][NS];
  const f32x4 zero = {0.f, 0.f, 0.f, 0.f};
#pragma unroll
  for (int m = 0; m < 8; ++m)
#pragma unroll
    for (int n = 0; n < NS; ++n) acc[m][n] = zero;

  // prologue: B(t0), A(t0), B(t1); wait t0 landed (B(t1) stays in flight)
#pragma unroll
  for (int ld = 0; ld < NS; ++ld)
    gload_lds16(gb + ld * 65536, pB0 + ld * 4096 + tid * 8);
#pragma unroll
  for (int ld = 0; ld < 4; ++ld)
    gload_lds16(ga + ld * 65536, pA0 + ld * 4096 + tid * 8);
#pragma unroll
  for (int ld = 0; ld < NS; ++ld)
    gload_lds16(gb + 64 + ld * 65536, pB1 + ld * 4096 + tid * 8);
  wait_vm<NS>();
  __builtin_amdgcn_s_barrier();

  // main loop: tiles 0..13 (full schedule); tail: 14 (A-stage only), 15
#pragma unroll 1
  for (int tp = 0; tp < 7; ++tp) {
    const int k1 = tp * 128;
    kiter8p<NS, true, true, NS>(acc, pA0, pB0, pA1, pB0,
                                ga + k1 + 64, gb + k1 + 128, tid,
                                aoff0, aoff1, boff0, boff1);
    kiter8p<NS, true, true, NS>(acc, pA1, pB1, pA0, pB1,
                                ga + k1 + 128, gb + k1 + 192, tid,
                                aoff0, aoff1, boff0, boff1);
  }
  kiter8p<NS, true, false, 0>(acc, pA0, pB0, pA1, pB0, ga + 960, gb, tid,
                              aoff0, aoff1, boff0, boff1);
  kiter8p<NS, false, false, -1>(acc, pA1, pB1, pA0, pB1, ga, gb, tid,
                                aoff0, aoff1, boff0, boff1);

  // ---- epilogue ----
  if (MODE == 1) {
    float* C = (float*)C0;
#pragma unroll
    for (int m = 0; m < 8; ++m) {
      const int rg = row0 + wm * 128 + m * 16 + quad * 4;
#pragma unroll
      for (int n = 0; n < NS; ++n) {
        const int cg = colm + wn * WN + n * 16 + l15;
#pragma unroll
        for (int r = 0; r < 4; ++r)
          C[(size_t)(rg + r) * 1024 + cg] = acc[m][n][r];
      }
    }
    return;
  }
  if (z == 2) {
    // V -> Vt[(b*16+h)*64+d][t], 8B t-contiguous vector stores
    u16* Vt = (u16*)C2;
#pragma unroll
    for (int m = 0; m < 8; ++m) {
      const int m0 = row0 + wm * 128 + m * 16 + quad * 4;  // token, r=0
      const int bb = m0 >> 11, t = m0 & 2047;
#pragma unroll
      for (int n = 0; n < NS; ++n) {
        const int cg = colm + wn * WN + n * 16 + l15;      // h*64 + d
        ushort4 w;
        w.x = f32_bf16(acc[m][n][0]);
        w.y = f32_bf16(acc[m][n][1]);
        w.z = f32_bf16(acc[m][n][2]);
        w.w = f32_bf16(acc[m][n][3]);
        *(ushort4*)(Vt + ((size_t)(bb * 16 + (cg >> 6)) * 64 + (cg & 63)) * 2048 + t) = w;
      }
    }
  } else {
    u16* C = (z == 0) ? (u16*)C0 : (u16*)C1;
    const float scale = (z == 0) ? qscale : 1.0f;
#pragma unroll
    for (int m = 0; m < 8; ++m) {
      const int rg = row0 + wm * 128 + m * 16 + quad * 4;
#pragma unroll
      for (int n = 0; n < NS; ++n) {
        const int cg = colm + wn * WN + n * 16 + l15;
#pragma unroll
        for (int r = 0; r < 4; ++r)
          C[(size_t)(rg + r) * 1024 + cg] = f32_bf16(acc[m][n][r] * scale);
      }
    }
  }
}

// ---------------------------------------------------------------------------
// Flash attention, causal. Q-tile 128 (4 waves x 32 q), 32-key tiles,
// ring-3 K/V LDS buffers, vmcnt(2)+s_barrier (prefetch stays in flight).
// Max-free softmax (m==0, Q pre-scaled by log2e/8), PV one tile behind QK.
// Balanced CU mapping (4 co-resident blocks/CU sum to constant causal work).
// Ks rows: slot = chunk ^ (row&7).  Vs rows: slot = chunk ^ ((row>>1)&3).
// ---------------------------------------------------------------------------
__global__ __launch_bounds__(256, 4) void attn_kernel(
    const u16* __restrict__ Qb, const u16* __restrict__ Kb,
    const u16* __restrict__ Vt, u16* __restrict__ Ob, int T) {
  __shared__ u16 Ks[3][32 * 64];   // ring: [key][feat-slot]
  __shared__ u16 Vs[3][64 * 32];   // ring: [d][key-slot]
  __shared__ u16 Ps[4][32 * 40];   // per-wave P^T: [q][key], stride 40

  // balanced (qblk, bh) decode
  const int ord = blockIdx.x;
  const int i4 = ord & 255, j4 = ord >> 8;
  const int qh = i4 & 15;
  const int base = (j4 & 2) ? (qh ^ 8) : qh;
  const int qblk = (j4 & 1) ? 15 - base : base;
  const int bh = (i4 >> 4) + 16 * j4;

  const int b = bh >> 4, h = bh & 15;
  const int tid = threadIdx.x, lane = tid & 63, wid = tid >> 6;
  const int quad = lane >> 4, l15 = lane & 15;
  const int qb0 = qblk * 128;
  const int D = 1024;
  const int sw = l15 & 7;          // K-row swizzle key
  const int swv = (l15 >> 1) & 3;  // V-row swizzle key

  // Q fragments (B-operand: n=l15 -> q, k=quad*8+j -> feat), 2 q-subtiles
  bf16x8 qf[2][2];
#pragma unroll
  for (int qs = 0; qs < 2; ++qs) {
    const int q = qb0 + wid * 32 + qs * 16 + l15;
    const u16* qp = Qb + ((size_t)b * T + q) * D + h * 64 + quad * 8;
    qf[qs][0] = *(const bf16x8*)(qp);
    qf[qs][1] = *(const bf16x8*)(qp + 32);
  }

  const f32x4 zero = {0.f, 0.f, 0.f, 0.f};
  f32x4 o[2][4];  // [q-subtile][d-subtile]
#pragma unroll
  for (int ms = 0; ms < 2; ++ms)
    for (int nt = 0; nt < 4; ++nt) o[ms][nt] = zero;
  float l_acc[2] = {0.f, 0.f};

  // pipelined PV fragments (held across one tile)
  bf16x8 vf_h[4];
  bf16x8 pf_h[2];

  // staging source addresses with XOR chunk swizzle
  const int krow = tid >> 3, kslot = tid & 7;
  const u16* kg = Kb + ((size_t)b * T + krow) * D + h * 64 + (kslot ^ (krow & 7)) * 8;
  const int vrow = tid >> 2, vslot = tid & 3;
  const u16* vg = Vt + ((size_t)bh * 64 + vrow) * T + (vslot ^ ((vrow >> 1) & 3)) * 8;

  const int ntiles = 4 * (qblk + 1);  // 32-key tiles, >= 4

  // prefetch tiles 0 and 1 (2 loads each)
  gload_lds16(kg, &Ks[0][tid * 8]);
  gload_lds16(vg, &Vs[0][tid * 8]);
  gload_lds16(kg + (size_t)32 * D, &Ks[1][tid * 8]);
  gload_lds16(vg + 32, &Vs[1][tid * 8]);
  barrier_vm2();  // tile-0 data landed; tile-1 loads may stay in flight

  int c = 0;  // ring index t % 3
  for (int t = 0; t < ntiles; ++t) {
    // prefetch tile t+2 (clamped dummy at the tail keeps vmcnt uniform)
    {
      int pb = c + 2; if (pb >= 3) pb -= 3;
      const int tp = (t + 2 < ntiles) ? t + 2 : ntiles - 1;
      const size_t kv = (size_t)tp * 32;
      gload_lds16(kg + kv * D, &Ks[pb][tid * 8]);
      gload_lds16(vg + kv, &Vs[pb][tid * 8]);
    }
    const int kv0 = t * 32;

    // --- QK(t): S^T[key][q], A = K rows (2 subtiles), B = Q (2 subtiles)
    f32x4 s[2][2];
#pragma unroll
    for (int st = 0; st < 2; ++st) {
      const int row = st * 16 + l15;
      const bf16x8 k0 = *(const bf16x8*)(&Ks[c][row * 64 + ((quad ^ sw) * 8)]);
      const bf16x8 k1 = *(const bf16x8*)(&Ks[c][row * 64 + (((4 + quad) ^ sw) * 8)]);
#pragma unroll
      for (int qs = 0; qs < 2; ++qs) {
        s[st][qs] = mfma16(k0, qf[qs][0], zero);
        s[st][qs] = mfma16(k1, qf[qs][1], s[st][qs]);
      }
    }

    // --- PV(t-1): independent of s(t); overlaps QK in the MFMA pipe
    if (t > 0) {
#pragma unroll
      for (int nt = 0; nt < 4; ++nt)
#pragma unroll
        for (int ms = 0; ms < 2; ++ms)
          o[ms][nt] = mfma16(pf_h[ms], vf_h[nt], o[ms][nt]);
    }

    // --- V(t) fragments into registers (independent of s)
#pragma unroll
    for (int nt = 0; nt < 4; ++nt)
      vf_h[nt] = *(const bf16x8*)(
          &Vs[c][(nt * 16 + l15) * 32 + ((quad ^ swv) * 8)]);

    // --- causal mask: last 4 tiles straddle the q-range [qb0, qb0+128)
    if (t >= ntiles - 4) {
#pragma unroll
      for (int qs = 0; qs < 2; ++qs) {
        const int q = qb0 + wid * 32 + qs * 16 + l15;
#pragma unroll
        for (int st = 0; st < 2; ++st)
#pragma unroll
          for (int r = 0; r < 4; ++r) {
            const int key = kv0 + st * 16 + quad * 4 + r;
            if (key > q) s[st][qs][r] = -INFINITY;
          }
      }
    }

    // --- max-free softmax: p = 2^s (Q pre-scaled by log2e); l per-lane
#pragma unroll
    for (int qs = 0; qs < 2; ++qs) {
      float sum = l_acc[qs];
#pragma unroll
      for (int st = 0; st < 2; ++st)
#pragma unroll
        for (int r = 0; r < 4; ++r) {
          const float p = __builtin_amdgcn_exp2f(s[st][qs][r]);
          s[st][qs][r] = p;
          sum += p;
        }
      l_acc[qs] = sum;
    }

    // --- P^T -> LDS (A-layout for PV), 8B vector stores, stride 40
#pragma unroll
    for (int qs = 0; qs < 2; ++qs)
#pragma unroll
      for (int st = 0; st < 2; ++st) {
        bf16x4 w;
        w[0] = (__bf16)s[st][qs][0];
        w[1] = (__bf16)s[st][qs][1];
        w[2] = (__bf16)s[st][qs][2];
        w[3] = (__bf16)s[st][qs][3];
        *(bf16x4*)(&Ps[wid][(qs * 16 + l15) * 40 + st * 16 + quad * 4]) = w;
      }

    // --- P(t) fragments for next iteration's PV (same-wave DS is in-order)
#pragma unroll
    for (int ms = 0; ms < 2; ++ms)
      pf_h[ms] = *(const bf16x8*)(&Ps[wid][(ms * 16 + l15) * 40 + quad * 8]);

    barrier_vm2();  // t+1 data landed; t+2 loads stay in flight
    ++c; if (c >= 3) c = 0;
  }

  // --- flush PV(last)
#pragma unroll
  for (int nt = 0; nt < 4; ++nt)
#pragma unroll
    for (int ms = 0; ms < 2; ++ms)
      o[ms][nt] = mfma16(pf_h[ms], vf_h[nt], o[ms][nt]);

  // epilogue: reduce l across the 4 quads (once), normalize, store
#pragma unroll
  for (int ms = 0; ms < 2; ++ms) {
    float sum = l_acc[ms];
    sum += __shfl_xor(sum, 16);
    sum += __shfl_xor(sum, 32);
    const float linv = 1.0f / sum;
    float lr[4];
#pragma unroll
    for (int r = 0; r < 4; ++r) lr[r] = __shfl(linv, quad * 4 + r);
#pragma unroll
    for (int r = 0; r < 4; ++r) {
      const int qo = qb0 + wid * 32 + ms * 16 + quad * 4 + r;
      u16* op = Ob + ((size_t)b * T + qo) * D + h * 64 + l15;
#pragma unroll
      for (int nt = 0; nt < 4; ++nt)
        op[nt * 16] = f32_bf16(o[ms][nt][r] * lr[r]);
    }
  }
}

// ---------------------------------------------------------------------------
extern "C" void kernel_launch(void* const* d_in, const int* in_sizes, int n_in,
                              void* d_out, int out_size, void* d_ws, size_t ws_size,
                              hipStream_t stream) {
  const float* x  = (const float*)d_in[0];
  const float* wq = (const float*)d_in[1];
  const float* wk = (const float*)d_in[2];
  const float* wv = (const float*)d_in[3];
  const float* wo = (const float*)d_in[4];

  const int B = 4, T = 2048, D = 1024;
  const int M = B * T;  // 8192

  u16* ws = (u16*)d_ws;
  u16* xb  = ws;                         // M*D
  u16* wqb = xb  + (size_t)M * D;        // D*D (contiguous with xb: fused cast)
  u16* wkb = wqb + (size_t)D * D;
  u16* wvb = wkb + (size_t)D * D;
  u16* wob = wvb + (size_t)D * D;
  u16* Qb  = wob + (size_t)D * D;        // M*D (pre-scaled by log2e/8)
  u16* Kb  = Qb  + (size_t)M * D;
  u16* Vt  = Kb  + (size_t)M * D;        // transposed V: [bh][d][t] (from GEMM)
  u16* Ob  = Vt  + (size_t)M * D;        // attention output

  // fused cast (dst regions xb..wob are contiguous)
  const int n_x = M * D / 4, n_w = D * D / 4;
  const int n_tot = n_x + 4 * n_w;
  cvt_all_kernel<<<(n_tot + 255) / 256, 256, 0, stream>>>(x, wq, wk, wv, wo,
                                                          xb, n_x, n_w);

  // fused QKV projection: 32 row-tiles x 12 col-tiles (256x256) = 384 blocks
  // Q scaled by (1/sqrt(Dh)) * log2(e)
  gemm8p<0><<<384, 512, 0, stream>>>(
      xb, wqb, wkb, wvb, Qb, Kb, Vt, 0.125f * 1.44269504f);

  // flash attention (balanced 1-D grid: 16 q-tiles x 64 bh = 1024 blocks)
  attn_kernel<<<dim3(1024), 256, 0, stream>>>(Qb, Kb, Vt, Ob, T);

  // output projection -> fp32 d_out: 32 x 8 (256x128) = 256 blocks (1 round)
  gemm8p<1><<<256, 512, 0, stream>>>(
      Ob, wob, wob, wob, d_out, d_out, d_out, 1.0f);
}

// Round 4
// 238.022 us; speedup vs baseline: 1.0889x; 1.0889x over previous
//
#include <hip/hip_runtime.h>
#include <cstdint>
#include <math.h>

// ---------------------------------------------------------------------------
// CausalSelfAttention (B=4, T=2048, D=1024, H=16, Dh=64), fp32 in/out,
// bf16 MFMA compute internally.
// Pipeline: fused cast -> fused QKV GEMM (128x384 tile, BK=64, 4-phase
//           READ-AHEAD schedule w/ counted lgkmcnt + counted vmcnt,
//           XOR-swizzled LDS, 512 blocks = 2 exact CU rounds, epilogue
//           routes cols to Q/K/Vt) -> flash attention (unchanged) ->
//           output projection (same template, 128x256, 256 blocks = 1 round).
//
// Key fix vs round 3 (MfmaUtil 24%, LDS/MFMA fully serialized): each phase
// issues the NEXT phase's ds_reads and waits a COUNTED lgkmcnt for only the
// previous phase's reads -> LDS service hides under the MFMA clusters.
// ---------------------------------------------------------------------------

typedef unsigned short u16;
typedef __bf16 bf16x8 __attribute__((ext_vector_type(8)));
typedef __bf16 bf16x4 __attribute__((ext_vector_type(4)));
typedef float f32x4 __attribute__((ext_vector_type(4)));

__device__ __forceinline__ u16 f32_bf16(float f) {  // round-nearest-even
  union { float f; uint32_t u; } c; c.f = f;
  uint32_t u = c.u;
  return (u16)((u + 0x7FFFu + ((u >> 16) & 1u)) >> 16);
}

__device__ __forceinline__ f32x4 mfma16(bf16x8 a, bf16x8 b, f32x4 c) {
  return __builtin_amdgcn_mfma_f32_16x16x32_bf16(a, b, c, 0, 0, 0);
}

// async global->LDS, 16B/lane. LDS dest must be wave-uniform base + lane*16.
__device__ __forceinline__ void gload_lds16(const u16* g, u16* l) {
  __builtin_amdgcn_global_load_lds(
      (const __attribute__((address_space(1))) void*)g,
      (__attribute__((address_space(3))) void*)l, 16, 0, 0);
}

template <int N>
__device__ __forceinline__ void wait_lgkm() {
  if (N == 0)       asm volatile("s_waitcnt lgkmcnt(0)" ::: "memory");
  else if (N == 4)  asm volatile("s_waitcnt lgkmcnt(4)" ::: "memory");
  else if (N == 8)  asm volatile("s_waitcnt lgkmcnt(8)" ::: "memory");
  else if (N == 10) asm volatile("s_waitcnt lgkmcnt(10)" ::: "memory");
  __builtin_amdgcn_sched_barrier(0);
}
template <int N>
__device__ __forceinline__ void wait_vm() {
  if (N == 6)      asm volatile("s_waitcnt vmcnt(6)" ::: "memory");
  else if (N == 4) asm volatile("s_waitcnt vmcnt(4)" ::: "memory");
  else if (N == 2) asm volatile("s_waitcnt vmcnt(2)" ::: "memory");
  else if (N == 0) asm volatile("s_waitcnt vmcnt(0)" ::: "memory");
  __builtin_amdgcn_sched_barrier(0);
}

// barrier that does NOT drain the newest 2 vm loads (attn t+2 prefetch)
__device__ __forceinline__ void barrier_vm2() {
  asm volatile("s_waitcnt vmcnt(2)" ::: "memory");
  __builtin_amdgcn_sched_barrier(0);
  __builtin_amdgcn_s_barrier();
}

// ---------------------------------------------------------------------------
// fused cast fp32->bf16 of x + 4 weights into contiguous ws region
// ---------------------------------------------------------------------------
__global__ __launch_bounds__(256) void cvt_all_kernel(
    const float* __restrict__ x,
    const float* __restrict__ wq, const float* __restrict__ wk,
    const float* __restrict__ wv, const float* __restrict__ wo,
    u16* __restrict__ dst, int n_x, int n_w) {
  int i = blockIdx.x * 256 + threadIdx.x;
  const float* src;
  int off;
  if (i < n_x) { src = x; off = i; }
  else {
    int j = i - n_x;
    int w = j / n_w;  off = j - w * n_w;
    src = (w == 0) ? wq : (w == 1) ? wk : (w == 2) ? wv : wo;
  }
  float4 f = ((const float4*)src)[off];
  ushort4 o;
  o.x = f32_bf16(f.x); o.y = f32_bf16(f.y);
  o.z = f32_bf16(f.z); o.w = f32_bf16(f.w);
  ((ushort4*)dst)[i] = o;
}

// ---------------------------------------------------------------------------
// Read-ahead GEMM: C[m,n] = sum_k A[m,k]*B[n,k] (both K-contiguous).
// BM=128, BN=NS*64 (QKV: NS=6 -> 384, proj: NS=4 -> 256), BK=64,
// 512 threads = 8 waves (2M x 4N), per-wave 64 x NS*16.
// LDS dbuf: As[2][128*64] (32 KB) + Bs[2][NS*64*64] (96/64 KB).
//
// Per K-tile t (cur = t&1), 4 phases, quadrant (mh,nh), MFMA/phase = NS:
//  ph0: issue ds bfB(2NB)+afB(4); stage A(t+1)(2);
//       lgkm(2NB+4) [drains prev-ph3 afA,bfA]; MFMA afA*bfA; BAR
//  ph1: lgkm(4) [drains bfB, leaves afB];      MFMA afA*bfB; BAR
//  ph2: stage B(t+2)(NS); vmcnt(NS) [drains A(t+1),B(t+1) -> tile t+1
//       landed, per-wave]; lgkm(0) [afB];      MFMA afB*bfA; BAR
//       (this BAR globalizes the vmcnt across waves)
//  ph3: issue ds afA,bfA for tile t+1 from the other buffer (safe: after
//       ph2's vmcnt+BAR); sched_barrier;        MFMA afB*bfB; BAR
// Counted waits keep ~10 ds_reads and NS+2 global loads in flight at all
// times -> LDS and matrix pipes overlap (round-3 serialized them: 24%).
//
// Staging safety: A(t+1)@ph0 overwrites A(t-1) (reads drained t-1 ph2,
// globalized by t-1 BAR2 < t ph0). B(t+2)@ph2 overwrites B(t) (bfB drained
// ph1, globalized BAR1 < ph2).  Tail: t=14 SA only + vmcnt(0); t=15 none.
//
// LDS swizzle (verified rounds 1-3, 0 conflicts): row-local, unchanged.
// ---------------------------------------------------------------------------
template <int NS, bool SA, bool SB, int VM, bool RD>
__device__ __forceinline__ void kiter(
    f32x4 (&acc)[4][NS], bf16x8 (&afA)[2][2], bf16x8 (&bfAr)[NS / 2][2],
    const u16* __restrict__ aCur, const u16* __restrict__ bCur,
    const u16* __restrict__ aNx, const u16* __restrict__ bNx,
    u16* aStg, u16* bStg,
    const u16* gaN, const u16* gbN2, int tid,
    int aoff0, int aoff1, int boff0, int boff1) {
  constexpr int NB = NS / 2;
  bf16x8 afB[2][2], bfB[NB][2];

  // ---- phase 0 ----
#pragma unroll
  for (int n = 0; n < NB; ++n) {  // bfB first (ph1 waits on it)
    bfB[n][0] = *(const bf16x8*)(bCur + boff0 + (NB + n) * 1024);
    bfB[n][1] = *(const bf16x8*)(bCur + boff1 + (NB + n) * 1024);
  }
#pragma unroll
  for (int m = 0; m < 2; ++m) {
    afB[m][0] = *(const bf16x8*)(aCur + aoff0 + (2 + m) * 1024);
    afB[m][1] = *(const bf16x8*)(aCur + aoff1 + (2 + m) * 1024);
  }
  if (SA) {
    gload_lds16(gaN, aStg + tid * 8);
    gload_lds16(gaN + 65536, aStg + 4096 + tid * 8);
  }
  wait_lgkm<2 * NB + 4>();
  __builtin_amdgcn_s_setprio(1);
#pragma unroll
  for (int m = 0; m < 2; ++m)
#pragma unroll
    for (int n = 0; n < NB; ++n) {
      acc[m][n] = mfma16(afA[m][0], bfAr[n][0], acc[m][n]);
      acc[m][n] = mfma16(afA[m][1], bfAr[n][1], acc[m][n]);
    }
  __builtin_amdgcn_s_setprio(0);
  __builtin_amdgcn_s_barrier();

  // ---- phase 1 ----
  wait_lgkm<4>();
  __builtin_amdgcn_s_setprio(1);
#pragma unroll
  for (int m = 0; m < 2; ++m)
#pragma unroll
    for (int n = 0; n < NB; ++n) {
      acc[m][NB + n] = mfma16(afA[m][0], bfB[n][0], acc[m][NB + n]);
      acc[m][NB + n] = mfma16(afA[m][1], bfB[n][1], acc[m][NB + n]);
    }
  __builtin_amdgcn_s_setprio(0);
  __builtin_amdgcn_s_barrier();

  // ---- phase 2 ----
  if (SB) {
#pragma unroll
    for (int ld = 0; ld < NS; ++ld)
      gload_lds16(gbN2 + ld * 65536, bStg + ld * 4096 + tid * 8);
  }
  if (VM >= 0) wait_vm<(VM >= 0 ? VM : 0)>();
  wait_lgkm<0>();
  __builtin_amdgcn_s_setprio(1);
#pragma unroll
  for (int m = 0; m < 2; ++m)
#pragma unroll
    for (int n = 0; n < NB; ++n) {
      acc[2 + m][n] = mfma16(afB[m][0], bfAr[n][0], acc[2 + m][n]);
      acc[2 + m][n] = mfma16(afB[m][1], bfAr[n][1], acc[2 + m][n]);
    }
  __builtin_amdgcn_s_setprio(0);
  __builtin_amdgcn_s_barrier();

  // ---- phase 3 ----
  if (RD) {
#pragma unroll
    for (int m = 0; m < 2; ++m) {  // afA first, then bfA (ph0 drains both)
      afA[m][0] = *(const bf16x8*)(aNx + aoff0 + m * 1024);
      afA[m][1] = *(const bf16x8*)(aNx + aoff1 + m * 1024);
    }
#pragma unroll
    for (int n = 0; n < NB; ++n) {
      bfAr[n][0] = *(const bf16x8*)(bNx + boff0 + n * 1024);
      bfAr[n][1] = *(const bf16x8*)(bNx + boff1 + n * 1024);
    }
    __builtin_amdgcn_sched_barrier(0);  // reads issued before this MFMA
  }
  __builtin_amdgcn_s_setprio(1);
#pragma unroll
  for (int m = 0; m < 2; ++m)
#pragma unroll
    for (int n = 0; n < NB; ++n) {
      acc[2 + m][NB + n] = mfma16(afB[m][0], bfB[n][0], acc[2 + m][NB + n]);
      acc[2 + m][NB + n] = mfma16(afB[m][1], bfB[n][1], acc[2 + m][NB + n]);
    }
  __builtin_amdgcn_s_setprio(0);
  __builtin_amdgcn_s_barrier();
}

template <int MODE>  // 0 = QKV (NS=6, routes cols to Q/K/Vt), 1 = proj (NS=4, fp32)
__global__ __launch_bounds__(512, 2) void gemm8p(
    const u16* __restrict__ A, const u16* __restrict__ Bc,
    u16* __restrict__ Qb, u16* __restrict__ Kb, u16* __restrict__ Vt,
    float* __restrict__ Cf, float qscale) {
  constexpr int NS = (MODE == 0) ? 6 : 4;   // n-subtiles per wave
  constexpr int NB = NS / 2;
  constexpr int WN = NS * 16;               // per-wave N (96 / 64)
  constexpr int K = 1024;
  __shared__ u16 As[2][8192];               // [dbuf][128 rows x 64 k]
  __shared__ u16 Bs[2][NS * 4096];          // [dbuf][NS*64 rows x 64 k]

  // XCD-bijective decode: per XCD 8 row-strips x (8 or 4) col-tiles
  const int ord = blockIdx.x;
  const int xcd = ord & 7, g = ord >> 3;
  const int rt = xcd * 8 + (g & 7);         // [0,64)
  const int ct = g >> 3;                    // MODE0: [0,8), MODE1: [0,4)
  const int colm = ct * (NS * 64);
  const int row0 = rt * 128;

  const int tid = threadIdx.x;
  const int lane = tid & 63, wid = tid >> 6;
  const int quad = lane >> 4, l15 = lane & 15;
  const int wm = wid >> 2, wn = wid & 3;

  // staging: linear LDS dest, pre-swizzled global source
  const int srow = tid >> 3;
  const int selem = ((tid & 7) ^ (srow & 7)) * 8;
  const u16* ga = A + (size_t)(row0 + srow) * K + selem;
  const u16* gb = Bc + (size_t)(colm + srow) * K + selem;

  u16* pA0 = &As[0][0];
  u16* pA1 = &As[1][0];
  u16* pB0 = &Bs[0][0];
  u16* pB1 = &Bs[1][0];

  // swizzled fragment read offsets (elements); row-local swizzle unchanged
  const int swz = 8 * (quad ^ (l15 & 3));
  const int kof = 32 * ((l15 >> 2) & 1);
  const int aoff0 = (wm * 64 + l15) * 64 + swz + kof;
  const int aoff1 = (wm * 64 + l15) * 64 + swz + (32 - kof);
  const int boff0 = (wn * WN + l15) * 64 + swz + kof;
  const int boff1 = (wn * WN + l15) * 64 + swz + (32 - kof);

  f32x4 acc[4][NS];
  const f32x4 zero = {0.f, 0.f, 0.f, 0.f};
#pragma unroll
  for (int m = 0; m < 4; ++m)
#pragma unroll
    for (int n = 0; n < NS; ++n) acc[m][n] = zero;

  bf16x8 afA[2][2], bfAr[NB][2];

  // prologue: stage A(0), B(0), B(1); vmcnt(NS) leaves B(1) in flight;
  // then pre-issue tile-0 ph0 fragments (afA, bfA)
  gload_lds16(ga, pA0 + tid * 8);
  gload_lds16(ga + 65536, pA0 + 4096 + tid * 8);
#pragma unroll
  for (int ld = 0; ld < NS; ++ld)
    gload_lds16(gb + ld * 65536, pB0 + ld * 4096 + tid * 8);
#pragma unroll
  for (int ld = 0; ld < NS; ++ld)
    gload_lds16(gb + 64 + ld * 65536, pB1 + ld * 4096 + tid * 8);
  wait_vm<NS>();
  __builtin_amdgcn_s_barrier();
#pragma unroll
  for (int m = 0; m < 2; ++m) {
    afA[m][0] = *(const bf16x8*)(pA0 + aoff0 + m * 1024);
    afA[m][1] = *(const bf16x8*)(pA0 + aoff1 + m * 1024);
  }
#pragma unroll
  for (int n = 0; n < NB; ++n) {
    bfAr[n][0] = *(const bf16x8*)(pB0 + boff0 + n * 1024);
    bfAr[n][1] = *(const bf16x8*)(pB0 + boff1 + n * 1024);
  }

  // main loop: t=0..13 (7 pairs); tail t=14 (stage A(15), vmcnt 0), t=15
#pragma unroll 1
  for (int tp = 0; tp < 7; ++tp) {
    const int kb = tp * 128;
    kiter<NS, true, true, NS, true>(acc, afA, bfAr, pA0, pB0, pA1, pB1,
                                    pA1, pB0, ga + kb + 64, gb + kb + 128,
                                    tid, aoff0, aoff1, boff0, boff1);
    kiter<NS, true, true, NS, true>(acc, afA, bfAr, pA1, pB1, pA0, pB0,
                                    pA0, pB1, ga + kb + 128, gb + kb + 192,
                                    tid, aoff0, aoff1, boff0, boff1);
  }
  kiter<NS, true, false, 0, true>(acc, afA, bfAr, pA0, pB0, pA1, pB1,
                                  pA1, pB0, ga + 960, gb,
                                  tid, aoff0, aoff1, boff0, boff1);
  kiter<NS, false, false, -1, false>(acc, afA, bfAr, pA1, pB1, pA0, pB0,
                                     pA0, pB1, ga, gb,
                                     tid, aoff0, aoff1, boff0, boff1);

  // ---- epilogue ----
  if (MODE == 1) {
#pragma unroll
    for (int m = 0; m < 4; ++m) {
      const int rg = row0 + wm * 64 + m * 16 + quad * 4;
#pragma unroll
      for (int n = 0; n < NS; ++n) {
        const int cg = colm + wn * WN + n * 16 + l15;
#pragma unroll
        for (int r = 0; r < 4; ++r)
          Cf[(size_t)(rg + r) * 1024 + cg] = acc[m][n][r];
      }
    }
    return;
  }
  // MODE 0: route each 16-col subtile to Q (scaled), K, or Vt (transposed)
#pragma unroll
  for (int m = 0; m < 4; ++m) {
    const int rg = row0 + wm * 64 + m * 16 + quad * 4;  // token row, r=0
    const int bb = rg >> 11, t = rg & 2047;
#pragma unroll
    for (int n = 0; n < NS; ++n) {
      const int cg0 = colm + wn * WN + n * 16;  // 16-aligned, never spans z
      const int z = cg0 >> 10;
      const int c1 = (cg0 & 1023) + l15;
      if (z == 2) {
        // V -> Vt[(b*16+h)*64+d][t], 8B t-contiguous vector store
        ushort4 w;
        w.x = f32_bf16(acc[m][n][0]);
        w.y = f32_bf16(acc[m][n][1]);
        w.z = f32_bf16(acc[m][n][2]);
        w.w = f32_bf16(acc[m][n][3]);
        *(ushort4*)(Vt + ((size_t)(bb * 16 + (c1 >> 6)) * 64 + (c1 & 63)) * 2048 + t) = w;
      } else {
        u16* C = z ? Kb : Qb;
        const float sc = z ? 1.0f : qscale;
#pragma unroll
        for (int r = 0; r < 4; ++r)
          C[(size_t)(rg + r) * 1024 + c1] = f32_bf16(acc[m][n][r] * sc);
      }
    }
  }
}

// ---------------------------------------------------------------------------
// Flash attention, causal. Q-tile 128 (4 waves x 32 q), 32-key tiles,
// ring-3 K/V LDS buffers, vmcnt(2)+s_barrier (prefetch stays in flight).
// Max-free softmax (m==0, Q pre-scaled by log2e/8), PV one tile behind QK.
// Balanced CU mapping (4 co-resident blocks/CU sum to constant causal work).
// Ks rows: slot = chunk ^ (row&7).  Vs rows: slot = chunk ^ ((row>>1)&3).
// ---------------------------------------------------------------------------
__global__ __launch_bounds__(256, 4) void attn_kernel(
    const u16* __restrict__ Qb, const u16* __restrict__ Kb,
    const u16* __restrict__ Vt, u16* __restrict__ Ob, int T) {
  __shared__ u16 Ks[3][32 * 64];   // ring: [key][feat-slot]
  __shared__ u16 Vs[3][64 * 32];   // ring: [d][key-slot]
  __shared__ u16 Ps[4][32 * 40];   // per-wave P^T: [q][key], stride 40

  // balanced (qblk, bh) decode
  const int ord = blockIdx.x;
  const int i4 = ord & 255, j4 = ord >> 8;
  const int qh = i4 & 15;
  const int base = (j4 & 2) ? (qh ^ 8) : qh;
  const int qblk = (j4 & 1) ? 15 - base : base;
  const int bh = (i4 >> 4) + 16 * j4;

  const int b = bh >> 4, h = bh & 15;
  const int tid = threadIdx.x, lane = tid & 63, wid = tid >> 6;
  const int quad = lane >> 4, l15 = lane & 15;
  const int qb0 = qblk * 128;
  const int D = 1024;
  const int sw = l15 & 7;          // K-row swizzle key
  const int swv = (l15 >> 1) & 3;  // V-row swizzle key

  // Q fragments (B-operand: n=l15 -> q, k=quad*8+j -> feat), 2 q-subtiles
  bf16x8 qf[2][2];
#pragma unroll
  for (int qs = 0; qs < 2; ++qs) {
    const int q = qb0 + wid * 32 + qs * 16 + l15;
    const u16* qp = Qb + ((size_t)b * T + q) * D + h * 64 + quad * 8;
    qf[qs][0] = *(const bf16x8*)(qp);
    qf[qs][1] = *(const bf16x8*)(qp + 32);
  }

  const f32x4 zero = {0.f, 0.f, 0.f, 0.f};
  f32x4 o[2][4];  // [q-subtile][d-subtile]
#pragma unroll
  for (int ms = 0; ms < 2; ++ms)
    for (int nt = 0; nt < 4; ++nt) o[ms][nt] = zero;
  float l_acc[2] = {0.f, 0.f};

  // pipelined PV fragments (held across one tile)
  bf16x8 vf_h[4];
  bf16x8 pf_h[2];

  // staging source addresses with XOR chunk swizzle
  const int krow = tid >> 3, kslot = tid & 7;
  const u16* kg = Kb + ((size_t)b * T + krow) * D + h * 64 + (kslot ^ (krow & 7)) * 8;
  const int vrow = tid >> 2, vslot = tid & 3;
  const u16* vg = Vt + ((size_t)bh * 64 + vrow) * T + (vslot ^ ((vrow >> 1) & 3)) * 8;

  const int ntiles = 4 * (qblk + 1);  // 32-key tiles, >= 4

  // prefetch tiles 0 and 1 (2 loads each)
  gload_lds16(kg, &Ks[0][tid * 8]);
  gload_lds16(vg, &Vs[0][tid * 8]);
  gload_lds16(kg + (size_t)32 * D, &Ks[1][tid * 8]);
  gload_lds16(vg + 32, &Vs[1][tid * 8]);
  barrier_vm2();  // tile-0 data landed; tile-1 loads may stay in flight

  int c = 0;  // ring index t % 3
  for (int t = 0; t < ntiles; ++t) {
    // prefetch tile t+2 (clamped dummy at the tail keeps vmcnt uniform)
    {
      int pb = c + 2; if (pb >= 3) pb -= 3;
      const int tp = (t + 2 < ntiles) ? t + 2 : ntiles - 1;
      const size_t kv = (size_t)tp * 32;
      gload_lds16(kg + kv * D, &Ks[pb][tid * 8]);
      gload_lds16(vg + kv, &Vs[pb][tid * 8]);
    }
    const int kv0 = t * 32;

    // --- QK(t): S^T[key][q], A = K rows (2 subtiles), B = Q (2 subtiles)
    f32x4 s[2][2];
#pragma unroll
    for (int st = 0; st < 2; ++st) {
      const int row = st * 16 + l15;
      const bf16x8 k0 = *(const bf16x8*)(&Ks[c][row * 64 + ((quad ^ sw) * 8)]);
      const bf16x8 k1 = *(const bf16x8*)(&Ks[c][row * 64 + (((4 + quad) ^ sw) * 8)]);
#pragma unroll
      for (int qs = 0; qs < 2; ++qs) {
        s[st][qs] = mfma16(k0, qf[qs][0], zero);
        s[st][qs] = mfma16(k1, qf[qs][1], s[st][qs]);
      }
    }

    // --- PV(t-1): independent of s(t); overlaps QK in the MFMA pipe
    if (t > 0) {
#pragma unroll
      for (int nt = 0; nt < 4; ++nt)
#pragma unroll
        for (int ms = 0; ms < 2; ++ms)
          o[ms][nt] = mfma16(pf_h[ms], vf_h[nt], o[ms][nt]);
    }

    // --- V(t) fragments into registers (independent of s)
#pragma unroll
    for (int nt = 0; nt < 4; ++nt)
      vf_h[nt] = *(const bf16x8*)(
          &Vs[c][(nt * 16 + l15) * 32 + ((quad ^ swv) * 8)]);

    // --- causal mask: last 4 tiles straddle the q-range [qb0, qb0+128)
    if (t >= ntiles - 4) {
#pragma unroll
      for (int qs = 0; qs < 2; ++qs) {
        const int q = qb0 + wid * 32 + qs * 16 + l15;
#pragma unroll
        for (int st = 0; st < 2; ++st)
#pragma unroll
          for (int r = 0; r < 4; ++r) {
            const int key = kv0 + st * 16 + quad * 4 + r;
            if (key > q) s[st][qs][r] = -INFINITY;
          }
      }
    }

    // --- max-free softmax: p = 2^s (Q pre-scaled by log2e); l per-lane
#pragma unroll
    for (int qs = 0; qs < 2; ++qs) {
      float sum = l_acc[qs];
#pragma unroll
      for (int st = 0; st < 2; ++st)
#pragma unroll
        for (int r = 0; r < 4; ++r) {
          const float p = __builtin_amdgcn_exp2f(s[st][qs][r]);
          s[st][qs][r] = p;
          sum += p;
        }
      l_acc[qs] = sum;
    }

    // --- P^T -> LDS (A-layout for PV), 8B vector stores, stride 40
#pragma unroll
    for (int qs = 0; qs < 2; ++qs)
#pragma unroll
      for (int st = 0; st < 2; ++st) {
        bf16x4 w;
        w[0] = (__bf16)s[st][qs][0];
        w[1] = (__bf16)s[st][qs][1];
        w[2] = (__bf16)s[st][qs][2];
        w[3] = (__bf16)s[st][qs][3];
        *(bf16x4*)(&Ps[wid][(qs * 16 + l15) * 40 + st * 16 + quad * 4]) = w;
      }

    // --- P(t) fragments for next iteration's PV (same-wave DS is in-order)
#pragma unroll
    for (int ms = 0; ms < 2; ++ms)
      pf_h[ms] = *(const bf16x8*)(&Ps[wid][(ms * 16 + l15) * 40 + quad * 8]);

    barrier_vm2();  // t+1 data landed; t+2 loads stay in flight
    ++c; if (c >= 3) c = 0;
  }

  // --- flush PV(last)
#pragma unroll
  for (int nt = 0; nt < 4; ++nt)
#pragma unroll
    for (int ms = 0; ms < 2; ++ms)
      o[ms][nt] = mfma16(pf_h[ms], vf_h[nt], o[ms][nt]);

  // epilogue: reduce l across the 4 quads (once), normalize, store
#pragma unroll
  for (int ms = 0; ms < 2; ++ms) {
    float sum = l_acc[ms];
    sum += __shfl_xor(sum, 16);
    sum += __shfl_xor(sum, 32);
    const float linv = 1.0f / sum;
    float lr[4];
#pragma unroll
    for (int r = 0; r < 4; ++r) lr[r] = __shfl(linv, quad * 4 + r);
#pragma unroll
    for (int r = 0; r < 4; ++r) {
      const int qo = qb0 + wid * 32 + ms * 16 + quad * 4 + r;
      u16* op = Ob + ((size_t)b * T + qo) * D + h * 64 + l15;
#pragma unroll
      for (int nt = 0; nt < 4; ++nt)
        op[nt * 16] = f32_bf16(o[ms][nt][r] * lr[r]);
    }
  }
}

// ---------------------------------------------------------------------------
extern "C" void kernel_launch(void* const* d_in, const int* in_sizes, int n_in,
                              void* d_out, int out_size, void* d_ws, size_t ws_size,
                              hipStream_t stream) {
  const float* x  = (const float*)d_in[0];
  const float* wq = (const float*)d_in[1];
  const float* wk = (const float*)d_in[2];
  const float* wv = (const float*)d_in[3];
  const float* wo = (const float*)d_in[4];

  const int B = 4, T = 2048, D = 1024;
  const int M = B * T;  // 8192

  u16* ws = (u16*)d_ws;
  u16* xb  = ws;                         // M*D
  u16* wqb = xb  + (size_t)M * D;        // D*D (contiguous with xb: fused cast;
  u16* wkb = wqb + (size_t)D * D;        //  wq/wk/wv contiguous -> one 3072x1024 B)
  u16* wvb = wkb + (size_t)D * D;
  u16* wob = wvb + (size_t)D * D;
  u16* Qb  = wob + (size_t)D * D;        // M*D (pre-scaled by log2e/8)
  u16* Kb  = Qb  + (size_t)M * D;
  u16* Vt  = Kb  + (size_t)M * D;        // transposed V: [bh][d][t] (from GEMM)
  u16* Ob  = Vt  + (size_t)M * D;        // attention output

  (void)wkb; (void)wvb;

  // fused cast (dst regions xb..wob are contiguous)
  const int n_x = M * D / 4, n_w = D * D / 4;
  const int n_tot = n_x + 4 * n_w;
  cvt_all_kernel<<<(n_tot + 255) / 256, 256, 0, stream>>>(x, wq, wk, wv, wo,
                                                          xb, n_x, n_w);

  // fused QKV projection: 64 row-tiles x 8 col-tiles (128x384) = 512 blocks
  // (2 exact rounds); Q scaled by (1/sqrt(Dh)) * log2(e)
  gemm8p<0><<<512, 512, 0, stream>>>(
      xb, wqb, Qb, Kb, Vt, nullptr, 0.125f * 1.44269504f);

  // flash attention (balanced 1-D grid: 16 q-tiles x 64 bh = 1024 blocks)
  attn_kernel<<<dim3(1024), 256, 0, stream>>>(Qb, Kb, Vt, Ob, T);

  // output projection -> fp32 d_out: 64 x 4 (128x256) = 256 blocks (1 round)
  gemm8p<1><<<256, 512, 0, stream>>>(
      Ob, wob, nullptr, nullptr, nullptr, (float*)d_out, 1.0f);
}

// Round 5
// 228.859 us; speedup vs baseline: 1.1325x; 1.0400x over previous
//
#include <hip/hip_runtime.h>
#include <cstdint>
#include <math.h>

// ---------------------------------------------------------------------------
// CausalSelfAttention (B=4, T=2048, D=1024, H=16, Dh=64), fp32 in/out,
// bf16 MFMA compute internally.
// Pipeline: fused cast -> fused QKV GEMM (128x384, read-ahead counted-lgkm
//           schedule, round 4) -> flash attention (NEW: 8-wave blocks, key
//           range split in half across wave-groups, in-LDS partial merge,
//           longest-first grid -> max block length 32 tiles instead of 64)
//           -> output projection (128x256, round 4).
//
// Round-5 rationale: attn was 67 us with OccupancyPercent 24.6% -- makespan
// was dominated by the single 64-tile qblk=15 block per CU running nearly
// alone at ~2350 cyc/wave-iter. Key-splitting halves the critical path and
// longest-first ordering lets short blocks backfill. Max-free softmax makes
// partials additive: merge = o_lo + o_hi, l_lo + l_hi (no rescale).
// ---------------------------------------------------------------------------

typedef unsigned short u16;
typedef __bf16 bf16x8 __attribute__((ext_vector_type(8)));
typedef __bf16 bf16x4 __attribute__((ext_vector_type(4)));
typedef float f32x4 __attribute__((ext_vector_type(4)));

__device__ __forceinline__ u16 f32_bf16(float f) {  // round-nearest-even
  union { float f; uint32_t u; } c; c.f = f;
  uint32_t u = c.u;
  return (u16)((u + 0x7FFFu + ((u >> 16) & 1u)) >> 16);
}

__device__ __forceinline__ f32x4 mfma16(bf16x8 a, bf16x8 b, f32x4 c) {
  return __builtin_amdgcn_mfma_f32_16x16x32_bf16(a, b, c, 0, 0, 0);
}

// async global->LDS, 16B/lane. LDS dest must be wave-uniform base + lane*16.
__device__ __forceinline__ void gload_lds16(const u16* g, u16* l) {
  __builtin_amdgcn_global_load_lds(
      (const __attribute__((address_space(1))) void*)g,
      (__attribute__((address_space(3))) void*)l, 16, 0, 0);
}

template <int N>
__device__ __forceinline__ void wait_lgkm() {
  if (N == 0)       asm volatile("s_waitcnt lgkmcnt(0)" ::: "memory");
  else if (N == 4)  asm volatile("s_waitcnt lgkmcnt(4)" ::: "memory");
  else if (N == 8)  asm volatile("s_waitcnt lgkmcnt(8)" ::: "memory");
  else if (N == 10) asm volatile("s_waitcnt lgkmcnt(10)" ::: "memory");
  __builtin_amdgcn_sched_barrier(0);
}
template <int N>
__device__ __forceinline__ void wait_vm() {
  if (N == 6)      asm volatile("s_waitcnt vmcnt(6)" ::: "memory");
  else if (N == 4) asm volatile("s_waitcnt vmcnt(4)" ::: "memory");
  else if (N == 2) asm volatile("s_waitcnt vmcnt(2)" ::: "memory");
  else if (N == 0) asm volatile("s_waitcnt vmcnt(0)" ::: "memory");
  __builtin_amdgcn_sched_barrier(0);
}

// barrier that does NOT drain the newest 2 vm loads (attn t+2 prefetch)
__device__ __forceinline__ void barrier_vm2() {
  asm volatile("s_waitcnt vmcnt(2)" ::: "memory");
  __builtin_amdgcn_sched_barrier(0);
  __builtin_amdgcn_s_barrier();
}

// ---------------------------------------------------------------------------
// fused cast fp32->bf16 of x + 4 weights into contiguous ws region
// ---------------------------------------------------------------------------
__global__ __launch_bounds__(256) void cvt_all_kernel(
    const float* __restrict__ x,
    const float* __restrict__ wq, const float* __restrict__ wk,
    const float* __restrict__ wv, const float* __restrict__ wo,
    u16* __restrict__ dst, int n_x, int n_w) {
  int i = blockIdx.x * 256 + threadIdx.x;
  const float* src;
  int off;
  if (i < n_x) { src = x; off = i; }
  else {
    int j = i - n_x;
    int w = j / n_w;  off = j - w * n_w;
    src = (w == 0) ? wq : (w == 1) ? wk : (w == 2) ? wv : wo;
  }
  float4 f = ((const float4*)src)[off];
  ushort4 o;
  o.x = f32_bf16(f.x); o.y = f32_bf16(f.y);
  o.z = f32_bf16(f.z); o.w = f32_bf16(f.w);
  ((ushort4*)dst)[i] = o;
}

// ---------------------------------------------------------------------------
// Read-ahead GEMM (unchanged from round 4): C[m,n] = sum_k A[m,k]*B[n,k].
// BM=128, BN=NS*64 (QKV: NS=6 -> 384, proj: NS=4 -> 256), BK=64,
// 512 threads = 8 waves (2M x 4N), per-wave 64 x NS*16.
// Per-phase: issue NEXT phase's ds_reads, counted lgkmcnt for the previous
// phase's -> LDS service hides under MFMA clusters. Counted vmcnt(NS),
// never 0 in the main loop.
// ---------------------------------------------------------------------------
template <int NS, bool SA, bool SB, int VM, bool RD>
__device__ __forceinline__ void kiter(
    f32x4 (&acc)[4][NS], bf16x8 (&afA)[2][2], bf16x8 (&bfAr)[NS / 2][2],
    const u16* __restrict__ aCur, const u16* __restrict__ bCur,
    const u16* __restrict__ aNx, const u16* __restrict__ bNx,
    u16* aStg, u16* bStg,
    const u16* gaN, const u16* gbN2, int tid,
    int aoff0, int aoff1, int boff0, int boff1) {
  constexpr int NB = NS / 2;
  bf16x8 afB[2][2], bfB[NB][2];

  // ---- phase 0 ----
#pragma unroll
  for (int n = 0; n < NB; ++n) {  // bfB first (ph1 waits on it)
    bfB[n][0] = *(const bf16x8*)(bCur + boff0 + (NB + n) * 1024);
    bfB[n][1] = *(const bf16x8*)(bCur + boff1 + (NB + n) * 1024);
  }
#pragma unroll
  for (int m = 0; m < 2; ++m) {
    afB[m][0] = *(const bf16x8*)(aCur + aoff0 + (2 + m) * 1024);
    afB[m][1] = *(const bf16x8*)(aCur + aoff1 + (2 + m) * 1024);
  }
  if (SA) {
    gload_lds16(gaN, aStg + tid * 8);
    gload_lds16(gaN + 65536, aStg + 4096 + tid * 8);
  }
  wait_lgkm<2 * NB + 4>();
  __builtin_amdgcn_s_setprio(1);
#pragma unroll
  for (int m = 0; m < 2; ++m)
#pragma unroll
    for (int n = 0; n < NB; ++n) {
      acc[m][n] = mfma16(afA[m][0], bfAr[n][0], acc[m][n]);
      acc[m][n] = mfma16(afA[m][1], bfAr[n][1], acc[m][n]);
    }
  __builtin_amdgcn_s_setprio(0);
  __builtin_amdgcn_s_barrier();

  // ---- phase 1 ----
  wait_lgkm<4>();
  __builtin_amdgcn_s_setprio(1);
#pragma unroll
  for (int m = 0; m < 2; ++m)
#pragma unroll
    for (int n = 0; n < NB; ++n) {
      acc[m][NB + n] = mfma16(afA[m][0], bfB[n][0], acc[m][NB + n]);
      acc[m][NB + n] = mfma16(afA[m][1], bfB[n][1], acc[m][NB + n]);
    }
  __builtin_amdgcn_s_setprio(0);
  __builtin_amdgcn_s_barrier();

  // ---- phase 2 ----
  if (SB) {
#pragma unroll
    for (int ld = 0; ld < NS; ++ld)
      gload_lds16(gbN2 + ld * 65536, bStg + ld * 4096 + tid * 8);
  }
  if (VM >= 0) wait_vm<(VM >= 0 ? VM : 0)>();
  wait_lgkm<0>();
  __builtin_amdgcn_s_setprio(1);
#pragma unroll
  for (int m = 0; m < 2; ++m)
#pragma unroll
    for (int n = 0; n < NB; ++n) {
      acc[2 + m][n] = mfma16(afB[m][0], bfAr[n][0], acc[2 + m][n]);
      acc[2 + m][n] = mfma16(afB[m][1], bfAr[n][1], acc[2 + m][n]);
    }
  __builtin_amdgcn_s_setprio(0);
  __builtin_amdgcn_s_barrier();

  // ---- phase 3 ----
  if (RD) {
#pragma unroll
    for (int m = 0; m < 2; ++m) {  // afA first, then bfA (ph0 drains both)
      afA[m][0] = *(const bf16x8*)(aNx + aoff0 + m * 1024);
      afA[m][1] = *(const bf16x8*)(aNx + aoff1 + m * 1024);
    }
#pragma unroll
    for (int n = 0; n < NB; ++n) {
      bfAr[n][0] = *(const bf16x8*)(bNx + boff0 + n * 1024);
      bfAr[n][1] = *(const bf16x8*)(bNx + boff1 + n * 1024);
    }
    __builtin_amdgcn_sched_barrier(0);  // reads issued before this MFMA
  }
  __builtin_amdgcn_s_setprio(1);
#pragma unroll
  for (int m = 0; m < 2; ++m)
#pragma unroll
    for (int n = 0; n < NB; ++n) {
      acc[2 + m][NB + n] = mfma16(afB[m][0], bfB[n][0], acc[2 + m][NB + n]);
      acc[2 + m][NB + n] = mfma16(afB[m][1], bfB[n][1], acc[2 + m][NB + n]);
    }
  __builtin_amdgcn_s_setprio(0);
  __builtin_amdgcn_s_barrier();
}

template <int MODE>  // 0 = QKV (NS=6, routes cols to Q/K/Vt), 1 = proj (NS=4, fp32)
__global__ __launch_bounds__(512, 2) void gemm8p(
    const u16* __restrict__ A, const u16* __restrict__ Bc,
    u16* __restrict__ Qb, u16* __restrict__ Kb, u16* __restrict__ Vt,
    float* __restrict__ Cf, float qscale) {
  constexpr int NS = (MODE == 0) ? 6 : 4;   // n-subtiles per wave
  constexpr int NB = NS / 2;
  constexpr int WN = NS * 16;               // per-wave N (96 / 64)
  constexpr int K = 1024;
  __shared__ u16 As[2][8192];               // [dbuf][128 rows x 64 k]
  __shared__ u16 Bs[2][NS * 4096];          // [dbuf][NS*64 rows x 64 k]

  // XCD-bijective decode: per XCD 8 row-strips x (8 or 4) col-tiles
  const int ord = blockIdx.x;
  const int xcd = ord & 7, g = ord >> 3;
  const int rt = xcd * 8 + (g & 7);         // [0,64)
  const int ct = g >> 3;                    // MODE0: [0,8), MODE1: [0,4)
  const int colm = ct * (NS * 64);
  const int row0 = rt * 128;

  const int tid = threadIdx.x;
  const int lane = tid & 63, wid = tid >> 6;
  const int quad = lane >> 4, l15 = lane & 15;
  const int wm = wid >> 2, wn = wid & 3;

  // staging: linear LDS dest, pre-swizzled global source
  const int srow = tid >> 3;
  const int selem = ((tid & 7) ^ (srow & 7)) * 8;
  const u16* ga = A + (size_t)(row0 + srow) * K + selem;
  const u16* gb = Bc + (size_t)(colm + srow) * K + selem;

  u16* pA0 = &As[0][0];
  u16* pA1 = &As[1][0];
  u16* pB0 = &Bs[0][0];
  u16* pB1 = &Bs[1][0];

  // swizzled fragment read offsets (elements); row-local swizzle unchanged
  const int swz = 8 * (quad ^ (l15 & 3));
  const int kof = 32 * ((l15 >> 2) & 1);
  const int aoff0 = (wm * 64 + l15) * 64 + swz + kof;
  const int aoff1 = (wm * 64 + l15) * 64 + swz + (32 - kof);
  const int boff0 = (wn * WN + l15) * 64 + swz + kof;
  const int boff1 = (wn * WN + l15) * 64 + swz + (32 - kof);

  f32x4 acc[4][NS];
  const f32x4 zero = {0.f, 0.f, 0.f, 0.f};
#pragma unroll
  for (int m = 0; m < 4; ++m)
#pragma unroll
    for (int n = 0; n < NS; ++n) acc[m][n] = zero;

  bf16x8 afA[2][2], bfAr[NB][2];

  // prologue: stage A(0), B(0), B(1); vmcnt(NS) leaves B(1) in flight;
  // then pre-issue tile-0 ph0 fragments (afA, bfA)
  gload_lds16(ga, pA0 + tid * 8);
  gload_lds16(ga + 65536, pA0 + 4096 + tid * 8);
#pragma unroll
  for (int ld = 0; ld < NS; ++ld)
    gload_lds16(gb + ld * 65536, pB0 + ld * 4096 + tid * 8);
#pragma unroll
  for (int ld = 0; ld < NS; ++ld)
    gload_lds16(gb + 64 + ld * 65536, pB1 + ld * 4096 + tid * 8);
  wait_vm<NS>();
  __builtin_amdgcn_s_barrier();
#pragma unroll
  for (int m = 0; m < 2; ++m) {
    afA[m][0] = *(const bf16x8*)(pA0 + aoff0 + m * 1024);
    afA[m][1] = *(const bf16x8*)(pA0 + aoff1 + m * 1024);
  }
#pragma unroll
  for (int n = 0; n < NB; ++n) {
    bfAr[n][0] = *(const bf16x8*)(pB0 + boff0 + n * 1024);
    bfAr[n][1] = *(const bf16x8*)(pB0 + boff1 + n * 1024);
  }

  // main loop: t=0..13 (7 pairs); tail t=14 (stage A(15), vmcnt 0), t=15
#pragma unroll 1
  for (int tp = 0; tp < 7; ++tp) {
    const int kb = tp * 128;
    kiter<NS, true, true, NS, true>(acc, afA, bfAr, pA0, pB0, pA1, pB1,
                                    pA1, pB0, ga + kb + 64, gb + kb + 128,
                                    tid, aoff0, aoff1, boff0, boff1);
    kiter<NS, true, true, NS, true>(acc, afA, bfAr, pA1, pB1, pA0, pB0,
                                    pA0, pB1, ga + kb + 128, gb + kb + 192,
                                    tid, aoff0, aoff1, boff0, boff1);
  }
  kiter<NS, true, false, 0, true>(acc, afA, bfAr, pA0, pB0, pA1, pB1,
                                  pA1, pB0, ga + 960, gb,
                                  tid, aoff0, aoff1, boff0, boff1);
  kiter<NS, false, false, -1, false>(acc, afA, bfAr, pA1, pB1, pA0, pB0,
                                     pA0, pB1, ga, gb,
                                     tid, aoff0, aoff1, boff0, boff1);

  // ---- epilogue ----
  if (MODE == 1) {
#pragma unroll
    for (int m = 0; m < 4; ++m) {
      const int rg = row0 + wm * 64 + m * 16 + quad * 4;
#pragma unroll
      for (int n = 0; n < NS; ++n) {
        const int cg = colm + wn * WN + n * 16 + l15;
#pragma unroll
        for (int r = 0; r < 4; ++r)
          Cf[(size_t)(rg + r) * 1024 + cg] = acc[m][n][r];
      }
    }
    return;
  }
  // MODE 0: route each 16-col subtile to Q (scaled), K, or Vt (transposed)
#pragma unroll
  for (int m = 0; m < 4; ++m) {
    const int rg = row0 + wm * 64 + m * 16 + quad * 4;  // token row, r=0
    const int bb = rg >> 11, t = rg & 2047;
#pragma unroll
    for (int n = 0; n < NS; ++n) {
      const int cg0 = colm + wn * WN + n * 16;  // 16-aligned, never spans z
      const int z = cg0 >> 10;
      const int c1 = (cg0 & 1023) + l15;
      if (z == 2) {
        // V -> Vt[(b*16+h)*64+d][t], 8B t-contiguous vector store
        ushort4 w;
        w.x = f32_bf16(acc[m][n][0]);
        w.y = f32_bf16(acc[m][n][1]);
        w.z = f32_bf16(acc[m][n][2]);
        w.w = f32_bf16(acc[m][n][3]);
        *(ushort4*)(Vt + ((size_t)(bb * 16 + (c1 >> 6)) * 64 + (c1 & 63)) * 2048 + t) = w;
      } else {
        u16* C = z ? Kb : Qb;
        const float sc = z ? 1.0f : qscale;
#pragma unroll
        for (int r = 0; r < 4; ++r)
          C[(size_t)(rg + r) * 1024 + c1] = f32_bf16(acc[m][n][r] * sc);
      }
    }
  }
}

// ---------------------------------------------------------------------------
// Flash attention, causal, KEY-SPLIT blocks. 512 threads = 8 waves:
//   waves 0-3 (half=0): q-tile rows, key tiles [0, n/2)
//   waves 4-7 (half=1): same q rows,  key tiles [n/2, n)
// n = 4*(qblk+1) is even -> both halves run EXACTLY n/2 iterations, so the
// block-wide barrier_vm2 per iter stays aligned. Each half streams its own
// ring-3 K/V LDS buffers (per-thread 2 gloads/iter -> vmcnt(2) unchanged).
// Max-free softmax (m==0, Q pre-scaled by log2e/8) -> partials are additive:
// after the loop, upper waves dump (o fp32, l) into the dead K/V LDS region,
// lower waves add, reduce l across quads, normalize, store.
// Mask: global tile gt = half*n/2 + t, mask iff gt >= n-4 (covers qblk=0).
// Grid: 1024 blocks, qblk = 15 - (ord>>6) -> longest blocks dispatch first.
// LDS 68 KB -> 2 blocks/CU = 16 waves sustained.
// ---------------------------------------------------------------------------
__global__ __launch_bounds__(512, 4) void attn_kernel(
    const u16* __restrict__ Qb, const u16* __restrict__ Kb,
    const u16* __restrict__ Vt, u16* __restrict__ Ob, int T) {
  // carve: Ks[2 str][3][2048] | Vs[2 str][3][2048] | Ps[8][1280]  (u16 units)
  __shared__ __align__(16) u16 smem[12288 * 2 + 8 * 1280];

  const int ord = blockIdx.x;
  const int qblk = 15 - (ord >> 6);   // longest first
  const int bh = ord & 63;
  const int b = bh >> 4, h = bh & 15;
  const int tid = threadIdx.x, lane = tid & 63, wid = tid >> 6;  // 0..7
  const int qwave = wid & 3, half = wid >> 2;
  const int quad = lane >> 4, l15 = lane & 15;
  const int qb0 = qblk * 128;
  const int D = 1024;
  const int sw = l15 & 7;          // K-row swizzle key
  const int swv = (l15 >> 1) & 3;  // V-row swizzle key

  const int n = 4 * (qblk + 1);    // total key tiles for this q-tile
  const int nt2 = n >> 1;          // per-stream tiles (>= 2)
  const int tb0 = half * nt2;      // global tile offset of this stream

  u16* KsB = smem + half * 6144;
  u16* VsB = smem + 12288 + half * 6144;
  u16* PsW = smem + 24576 + wid * 1280;

  // Q fragments (B-operand: n=l15 -> q, k=quad*8+j -> feat), 2 q-subtiles
  bf16x8 qf[2][2];
#pragma unroll
  for (int qs = 0; qs < 2; ++qs) {
    const int q = qb0 + qwave * 32 + qs * 16 + l15;
    const u16* qp = Qb + ((size_t)b * T + q) * D + h * 64 + quad * 8;
    qf[qs][0] = *(const bf16x8*)(qp);
    qf[qs][1] = *(const bf16x8*)(qp + 32);
  }

  const f32x4 zero = {0.f, 0.f, 0.f, 0.f};
  f32x4 o[2][4];  // [q-subtile][d-subtile]
#pragma unroll
  for (int ms = 0; ms < 2; ++ms)
    for (int nt = 0; nt < 4; ++nt) o[ms][nt] = zero;
  float l_acc[2] = {0.f, 0.f};

  bf16x8 vf_h[4];
  bf16x8 pf_h[2];

  // staging source addresses (group-local tid, per-stream key base)
  const int t256 = tid & 255;
  const int krow = t256 >> 3, kslot = t256 & 7;
  const u16* kg = Kb + ((size_t)b * T + tb0 * 32 + krow) * D + h * 64 +
                  (kslot ^ (krow & 7)) * 8;
  const int vrow = t256 >> 2, vslot = t256 & 3;
  const u16* vg = Vt + ((size_t)bh * 64 + vrow) * T + tb0 * 32 +
                  (vslot ^ ((vrow >> 1) & 3)) * 8;

  // prefetch tiles 0 and 1 of this stream
  gload_lds16(kg, KsB + t256 * 8);
  gload_lds16(vg, VsB + t256 * 8);
  gload_lds16(kg + (size_t)32 * D, KsB + 2048 + t256 * 8);
  gload_lds16(vg + 32, VsB + 2048 + t256 * 8);
  barrier_vm2();  // tile-0 data landed; tile-1 loads may stay in flight

  int c = 0;  // ring index t % 3
  for (int t = 0; t < nt2; ++t) {
    // prefetch tile t+2 (clamped dummy at the tail keeps vmcnt uniform)
    {
      int pb = c + 2; if (pb >= 3) pb -= 3;
      const int tp = (t + 2 < nt2) ? t + 2 : nt2 - 1;
      const size_t kv = (size_t)tp * 32;
      gload_lds16(kg + kv * D, KsB + pb * 2048 + t256 * 8);
      gload_lds16(vg + kv, VsB + pb * 2048 + t256 * 8);
    }
    const u16* KsC = KsB + c * 2048;
    const u16* VsC = VsB + c * 2048;
    const int gt = tb0 + t;          // global key-tile index
    const int kv0 = gt * 32;

    // --- QK(t): S^T[key][q], A = K rows (2 subtiles), B = Q (2 subtiles)
    f32x4 s[2][2];
#pragma unroll
    for (int st = 0; st < 2; ++st) {
      const int row = st * 16 + l15;
      const bf16x8 k0 = *(const bf16x8*)(&KsC[row * 64 + ((quad ^ sw) * 8)]);
      const bf16x8 k1 = *(const bf16x8*)(&KsC[row * 64 + (((4 + quad) ^ sw) * 8)]);
#pragma unroll
      for (int qs = 0; qs < 2; ++qs) {
        s[st][qs] = mfma16(k0, qf[qs][0], zero);
        s[st][qs] = mfma16(k1, qf[qs][1], s[st][qs]);
      }
    }

    // --- PV(t-1): independent of s(t); overlaps QK in the MFMA pipe
    if (t > 0) {
#pragma unroll
      for (int nt = 0; nt < 4; ++nt)
#pragma unroll
        for (int ms = 0; ms < 2; ++ms)
          o[ms][nt] = mfma16(pf_h[ms], vf_h[nt], o[ms][nt]);
    }

    // --- V(t) fragments into registers (independent of s)
#pragma unroll
    for (int nt = 0; nt < 4; ++nt)
      vf_h[nt] = *(const bf16x8*)(
          &VsC[(nt * 16 + l15) * 32 + ((quad ^ swv) * 8)]);

    // --- causal mask: global tile gt >= n-4 straddles the q-range
    if (gt >= n - 4) {
#pragma unroll
      for (int qs = 0; qs < 2; ++qs) {
        const int q = qb0 + qwave * 32 + qs * 16 + l15;
#pragma unroll
        for (int st = 0; st < 2; ++st)
#pragma unroll
          for (int r = 0; r < 4; ++r) {
            const int key = kv0 + st * 16 + quad * 4 + r;
            if (key > q) s[st][qs][r] = -INFINITY;
          }
      }
    }

    // --- max-free softmax: p = 2^s (Q pre-scaled by log2e); l per-lane
#pragma unroll
    for (int qs = 0; qs < 2; ++qs) {
      float sum = l_acc[qs];
#pragma unroll
      for (int st = 0; st < 2; ++st)
#pragma unroll
        for (int r = 0; r < 4; ++r) {
          const float p = __builtin_amdgcn_exp2f(s[st][qs][r]);
          s[st][qs][r] = p;
          sum += p;
        }
      l_acc[qs] = sum;
    }

    // --- P^T -> LDS (A-layout for PV), 8B vector stores, stride 40
#pragma unroll
    for (int qs = 0; qs < 2; ++qs)
#pragma unroll
      for (int st = 0; st < 2; ++st) {
        bf16x4 w;
        w[0] = (__bf16)s[st][qs][0];
        w[1] = (__bf16)s[st][qs][1];
        w[2] = (__bf16)s[st][qs][2];
        w[3] = (__bf16)s[st][qs][3];
        *(bf16x4*)(&PsW[(qs * 16 + l15) * 40 + st * 16 + quad * 4]) = w;
      }

    // --- P(t) fragments for next iteration's PV (same-wave DS is in-order)
#pragma unroll
    for (int ms = 0; ms < 2; ++ms)
      pf_h[ms] = *(const bf16x8*)(&PsW[(ms * 16 + l15) * 40 + quad * 8]);

    barrier_vm2();  // t+1 data landed; t+2 loads stay in flight
    ++c; if (c >= 3) c = 0;
  }

  // --- flush PV(last)
#pragma unroll
  for (int nt = 0; nt < 4; ++nt)
#pragma unroll
    for (int ms = 0; ms < 2; ++ms)
      o[ms][nt] = mfma16(pf_h[ms], vf_h[nt], o[ms][nt]);

  // --- merge halves via LDS (overlaid on K/V rings; drain async loads 1st)
  wait_vm<0>();
  __syncthreads();
  float* mo = (float*)smem;            // [4][64][32] f32 (32 KB)
  float* ml = (float*)smem + 8192;     // [4][64][2]  f32 (2 KB)
  if (half == 1) {
    float* dst = mo + (qwave * 64 + lane) * 32;
#pragma unroll
    for (int ms = 0; ms < 2; ++ms)
#pragma unroll
      for (int nt = 0; nt < 4; ++nt)
#pragma unroll
        for (int r = 0; r < 4; ++r)
          dst[ms * 16 + nt * 4 + r] = o[ms][nt][r];
    ml[(qwave * 64 + lane) * 2 + 0] = l_acc[0];
    ml[(qwave * 64 + lane) * 2 + 1] = l_acc[1];
  }
  __syncthreads();
  if (half == 1) return;
  {
    const float* src = mo + (qwave * 64 + lane) * 32;
#pragma unroll
    for (int ms = 0; ms < 2; ++ms)
#pragma unroll
      for (int nt = 0; nt < 4; ++nt)
#pragma unroll
        for (int r = 0; r < 4; ++r)
          o[ms][nt][r] += src[ms * 16 + nt * 4 + r];
    l_acc[0] += ml[(qwave * 64 + lane) * 2 + 0];
    l_acc[1] += ml[(qwave * 64 + lane) * 2 + 1];
  }

  // epilogue: reduce l across the 4 quads (once), normalize, store
#pragma unroll
  for (int ms = 0; ms < 2; ++ms) {
    float sum = l_acc[ms];
    sum += __shfl_xor(sum, 16);
    sum += __shfl_xor(sum, 32);
    const float linv = 1.0f / sum;
    float lr[4];
#pragma unroll
    for (int r = 0; r < 4; ++r) lr[r] = __shfl(linv, quad * 4 + r);
#pragma unroll
    for (int r = 0; r < 4; ++r) {
      const int qo = qb0 + qwave * 32 + ms * 16 + quad * 4 + r;
      u16* op = Ob + ((size_t)b * T + qo) * D + h * 64 + l15;
#pragma unroll
      for (int nt = 0; nt < 4; ++nt)
        op[nt * 16] = f32_bf16(o[ms][nt][r] * lr[r]);
    }
  }
}

// ---------------------------------------------------------------------------
extern "C" void kernel_launch(void* const* d_in, const int* in_sizes, int n_in,
                              void* d_out, int out_size, void* d_ws, size_t ws_size,
                              hipStream_t stream) {
  const float* x  = (const float*)d_in[0];
  const float* wq = (const float*)d_in[1];
  const float* wk = (const float*)d_in[2];
  const float* wv = (const float*)d_in[3];
  const float* wo = (const float*)d_in[4];

  const int B = 4, T = 2048, D = 1024;
  const int M = B * T;  // 8192

  u16* ws = (u16*)d_ws;
  u16* xb  = ws;                         // M*D
  u16* wqb = xb  + (size_t)M * D;        // D*D (contiguous with xb: fused cast;
  u16* wkb = wqb + (size_t)D * D;        //  wq/wk/wv contiguous -> one 3072x1024 B)
  u16* wvb = wkb + (size_t)D * D;
  u16* wob = wvb + (size_t)D * D;
  u16* Qb  = wob + (size_t)D * D;        // M*D (pre-scaled by log2e/8)
  u16* Kb  = Qb  + (size_t)M * D;
  u16* Vt  = Kb  + (size_t)M * D;        // transposed V: [bh][d][t] (from GEMM)
  u16* Ob  = Vt  + (size_t)M * D;        // attention output

  (void)wkb; (void)wvb;

  // fused cast (dst regions xb..wob are contiguous)
  const int n_x = M * D / 4, n_w = D * D / 4;
  const int n_tot = n_x + 4 * n_w;
  cvt_all_kernel<<<(n_tot + 255) / 256, 256, 0, stream>>>(x, wq, wk, wv, wo,
                                                          xb, n_x, n_w);

  // fused QKV projection: 64 row-tiles x 8 col-tiles (128x384) = 512 blocks
  // (2 exact rounds); Q scaled by (1/sqrt(Dh)) * log2(e)
  gemm8p<0><<<512, 512, 0, stream>>>(
      xb, wqb, Qb, Kb, Vt, nullptr, 0.125f * 1.44269504f);

  // flash attention: 16 q-tiles x 64 bh = 1024 blocks of 512 threads,
  // key-split halves in-block, longest blocks dispatched first
  attn_kernel<<<dim3(1024), 512, 0, stream>>>(Qb, Kb, Vt, Ob, T);

  // output projection -> fp32 d_out: 64 x 4 (128x256) = 256 blocks (1 round)
  gemm8p<1><<<256, 512, 0, stream>>>(
      Ob, wob, nullptr, nullptr, nullptr, (float*)d_out, 1.0f);
}